// Round 1
// baseline (664.811 us; speedup 1.0000x reference)
//
#include <hip/hip_runtime.h>

// Problem constants
#define L_TOT 2304   // 48*48
#define D_IN  64
#define NF    32     // features per head
#define NH    8      // heads
#define NB    2      // batch
#define MW    256    // MLP width = NH*NF

constexpr float EPSV  = 1e-5f;
constexpr float SCALE = 0.17677669529663687f;  // 1/sqrt(32)

// ---------------------------------------------------------------------------
// Kernel 1: fused projection (Q,K,V) + bias + InstanceNorm(last dim=32) + ReLU
// block = 256 threads (8 heads x 32 features), each block does 16 l-rows of one n
// grid = NB * (L_TOT/16) = 288
// ---------------------------------------------------------------------------
__global__ __launch_bounds__(256) void k_proj(
    const float* __restrict__ x,
    const float* __restrict__ Wq, const float* __restrict__ bq,
    const float* __restrict__ Wk, const float* __restrict__ bk,
    const float* __restrict__ Wv, const float* __restrict__ bv,
    float* __restrict__ Qo, float* __restrict__ Ko, float* __restrict__ Vo)
{
    const int tile = blockIdx.x;
    const int n  = tile / (L_TOT / 16);
    const int l0 = (tile % (L_TOT / 16)) * 16;
    const int tid = threadIdx.x;
    const int h = tid >> 5, f = tid & 31;

    __shared__ float xs[16][D_IN];
    // flat[n, l, d] = x[n*64*2304 + d*2304 + l]
    for (int i = tid; i < 16 * D_IN; i += 256) {
        int d = i >> 4, r = i & 15;
        xs[r][d] = x[n * D_IN * L_TOT + d * L_TOT + l0 + r];
    }
    __syncthreads();

    const float* Ws[3] = {Wq, Wk, Wv};
    const float* bs[3] = {bq, bk, bv};
    float*       Os[3] = {Qo, Ko, Vo};

    #pragma unroll
    for (int mtx = 0; mtx < 3; ++mtx) {
        float acc[16];
        #pragma unroll
        for (int r = 0; r < 16; ++r) acc[r] = 0.f;
        const float* W = Ws[mtx] + h * D_IN * NF + f;
        for (int d = 0; d < D_IN; ++d) {
            float w = W[d * NF];
            #pragma unroll
            for (int r = 0; r < 16; ++r) acc[r] += xs[r][d] * w;
        }
        const float bias = bs[mtx][h * NF + f];
        float* O = Os[mtx] + ((size_t)(h * NB + n) * L_TOT + l0) * NF + f;
        #pragma unroll
        for (int r = 0; r < 16; ++r) {
            float v = acc[r] + bias;
            float s = v, s2 = v * v;
            #pragma unroll
            for (int o = 16; o >= 1; o >>= 1) {
                s  += __shfl_xor(s,  o, 32);
                s2 += __shfl_xor(s2, o, 32);
            }
            float mu  = s  * (1.f / 32);
            float var = s2 * (1.f / 32) - mu * mu;
            float y = (v - mu) * rsqrtf(var + EPSV);
            O[r * NF] = fmaxf(y, 0.f);
        }
    }
}

// ---------------------------------------------------------------------------
// Kernel 2: per-column (m) softmax stats over l: partial max + sumexp per l-chunk
// grid = (16 hn, 9 m-tiles, CH chunks), block = 256 (one m per thread)
// ---------------------------------------------------------------------------
__global__ __launch_bounds__(256) void k_colstats(
    const float* __restrict__ Q, const float* __restrict__ K,
    float* __restrict__ cpart, float* __restrict__ zpart, int CH)
{
    const int hn = blockIdx.x;
    const int m  = blockIdx.y * 256 + threadIdx.x;
    const int chunk = blockIdx.z;
    const int Lc = L_TOT / CH;
    const int lbeg = chunk * Lc;

    float4 k4[8];
    const float4* Kp = (const float4*)(K + ((size_t)hn * L_TOT + m) * NF);
    #pragma unroll
    for (int j = 0; j < 8; ++j) k4[j] = Kp[j];

    __shared__ float4 qs[32 * 8];
    float mr = -INFINITY, Z = 0.f;

    for (int lt = 0; lt < Lc; lt += 32) {
        __syncthreads();
        const float4* Qp = (const float4*)(Q + ((size_t)hn * L_TOT + lbeg + lt) * NF);
        for (int i = threadIdx.x; i < 32 * 8; i += 256) qs[i] = Qp[i];
        __syncthreads();
        #pragma unroll 4
        for (int l = 0; l < 32; ++l) {
            float s = 0.f;
            #pragma unroll
            for (int j = 0; j < 8; ++j) {
                float4 q = qs[l * 8 + j];
                s += q.x * k4[j].x + q.y * k4[j].y + q.z * k4[j].z + q.w * k4[j].w;
            }
            s *= SCALE;
            float nm = fmaxf(mr, s);
            Z = Z * __expf(mr - nm) + __expf(s - nm);
            mr = nm;
        }
    }
    cpart[((size_t)chunk * 16 + hn) * L_TOT + m] = mr;
    zpart[((size_t)chunk * 16 + hn) * L_TOT + m] = Z;
}

// Combine chunked stats -> cmax, 1/Z
__global__ __launch_bounds__(256) void k_colfinish(
    const float* __restrict__ cpart, const float* __restrict__ zpart,
    float* __restrict__ cmax, float* __restrict__ zinv, int CH)
{
    const int idx = blockIdx.x * 256 + threadIdx.x;  // hn*L + m
    float c = -INFINITY;
    for (int k = 0; k < CH; ++k) c = fmaxf(c, cpart[(size_t)k * 16 * L_TOT + idx]);
    float Z = 0.f;
    for (int k = 0; k < CH; ++k)
        Z += zpart[(size_t)k * 16 * L_TOT + idx] * __expf(cpart[(size_t)k * 16 * L_TOT + idx] - c);
    cmax[idx] = c;
    zinv[idx] = 1.f / Z;
}

// ---------------------------------------------------------------------------
// Kernel 3: A[l,f] = sum_m exp(s[l,m]-c[m])*zinv[m] * V[m,f], chunked over m.
// Writes partials in heads layout: partA[chunk][n][l][h*32+f]
// grid = (16 hn, 9 l-tiles, CH chunks), block = 256 (one l per thread)
// ---------------------------------------------------------------------------
__global__ __launch_bounds__(256) void k_attn(
    const float* __restrict__ Q, const float* __restrict__ K, const float* __restrict__ V,
    const float* __restrict__ cmax, const float* __restrict__ zinv,
    float* __restrict__ partA, int CH)
{
    const int hn = blockIdx.x;
    const int l  = blockIdx.y * 256 + threadIdx.x;
    const int chunk = blockIdx.z;
    const int Mc = L_TOT / CH;
    const int mbeg = chunk * Mc;
    const int h = hn >> 1, n = hn & 1;

    float4 q4[8];
    const float4* Qp = (const float4*)(Q + ((size_t)hn * L_TOT + l) * NF);
    #pragma unroll
    for (int j = 0; j < 8; ++j) q4[j] = Qp[j];

    float4 a4[8];
    #pragma unroll
    for (int j = 0; j < 8; ++j) a4[j] = make_float4(0.f, 0.f, 0.f, 0.f);

    __shared__ float4 ks[32 * 8];
    __shared__ float4 vs[32 * 8];
    __shared__ float  cs[32];
    __shared__ float  zs[32];

    for (int mt = 0; mt < Mc; mt += 32) {
        __syncthreads();
        const int mbase = mbeg + mt;
        const float4* Kp = (const float4*)(K + ((size_t)hn * L_TOT + mbase) * NF);
        const float4* Vp = (const float4*)(V + ((size_t)hn * L_TOT + mbase) * NF);
        for (int i = threadIdx.x; i < 32 * 8; i += 256) { ks[i] = Kp[i]; vs[i] = Vp[i]; }
        if (threadIdx.x < 32) {
            cs[threadIdx.x] = cmax[(size_t)hn * L_TOT + mbase + threadIdx.x];
            zs[threadIdx.x] = zinv[(size_t)hn * L_TOT + mbase + threadIdx.x];
        }
        __syncthreads();
        #pragma unroll 4
        for (int m = 0; m < 32; ++m) {
            float s = 0.f;
            #pragma unroll
            for (int j = 0; j < 8; ++j) {
                float4 k = ks[m * 8 + j];
                s += q4[j].x * k.x + q4[j].y * k.y + q4[j].z * k.z + q4[j].w * k.w;
            }
            float p = __expf(s * SCALE - cs[m]) * zs[m];
            #pragma unroll
            for (int j = 0; j < 8; ++j) {
                float4 v = vs[m * 8 + j];
                a4[j].x += p * v.x; a4[j].y += p * v.y;
                a4[j].z += p * v.z; a4[j].w += p * v.w;
            }
        }
    }
    float4* Ap = (float4*)(partA + (size_t)chunk * (NB * L_TOT * MW)
                                 + ((size_t)n * L_TOT + l) * MW + h * NF);
    #pragma unroll
    for (int j = 0; j < 8; ++j) Ap[j] = a4[j];
}

// ---------------------------------------------------------------------------
// Kernel 4: heads = sum(partA) ; m=relu(relu(h@W1+b1)@W2+b2) ;
//           o = gamma*inorm(m+h)+beta ; out[n,c,l] (transposed store)
// block = 256 (one output channel c per thread), 16 l-rows per block
// ---------------------------------------------------------------------------
__global__ __launch_bounds__(256) void k_mlp(
    const float* __restrict__ partA,
    const float* __restrict__ W1, const float* __restrict__ b1,
    const float* __restrict__ W2, const float* __restrict__ b2,
    const float* __restrict__ gamma, const float* __restrict__ beta,
    float* __restrict__ out, int CH)
{
    const int tile = blockIdx.x;
    const int n  = tile / (L_TOT / 16);
    const int l0 = (tile % (L_TOT / 16)) * 16;
    const int c = threadIdx.x;
    const int wid = c >> 6, lane = c & 63;

    __shared__ float hs[16][MW];
    __shared__ float ms[16][MW];

    for (int idx = threadIdx.x; idx < 16 * MW; idx += 256) {
        int r = idx >> 8, i = idx & 255;
        float v = 0.f;
        for (int k = 0; k < CH; ++k)
            v += partA[(size_t)k * (NB * L_TOT * MW) + ((size_t)n * L_TOT + l0 + r) * MW + i];
        hs[r][i] = v;
    }
    __syncthreads();

    float acc[16];
    #pragma unroll
    for (int r = 0; r < 16; ++r) acc[r] = 0.f;
    for (int i = 0; i < MW; i += 4) {
        float w0 = W1[(i + 0) * MW + c];
        float w1 = W1[(i + 1) * MW + c];
        float w2 = W1[(i + 2) * MW + c];
        float w3 = W1[(i + 3) * MW + c];
        #pragma unroll
        for (int r = 0; r < 16; ++r) {
            const float4 h4 = *(const float4*)&hs[r][i];
            acc[r] += h4.x * w0 + h4.y * w1 + h4.z * w2 + h4.w * w3;
        }
    }
    {
        const float bb = b1[c];
        #pragma unroll
        for (int r = 0; r < 16; ++r) ms[r][c] = fmaxf(acc[r] + bb, 0.f);
    }
    __syncthreads();

    #pragma unroll
    for (int r = 0; r < 16; ++r) acc[r] = 0.f;
    for (int i = 0; i < MW; i += 4) {
        float w0 = W2[(i + 0) * MW + c];
        float w1 = W2[(i + 1) * MW + c];
        float w2 = W2[(i + 2) * MW + c];
        float w3 = W2[(i + 3) * MW + c];
        #pragma unroll
        for (int r = 0; r < 16; ++r) {
            const float4 h4 = *(const float4*)&ms[r][i];
            acc[r] += h4.x * w0 + h4.y * w1 + h4.z * w2 + h4.w * w3;
        }
    }

    float y[16];
    {
        const float bb = b2[c];
        #pragma unroll
        for (int r = 0; r < 16; ++r) y[r] = fmaxf(acc[r] + bb, 0.f) + hs[r][c];
    }

    __shared__ float rs[16][4], rs2[16][4];
    #pragma unroll
    for (int r = 0; r < 16; ++r) {
        float s = y[r], s2 = y[r] * y[r];
        #pragma unroll
        for (int o = 32; o >= 1; o >>= 1) { s += __shfl_xor(s, o, 64); s2 += __shfl_xor(s2, o, 64); }
        if (lane == 0) { rs[r][wid] = s; rs2[r][wid] = s2; }
    }
    __syncthreads();

    const float g = gamma[c], be = beta[c];
    #pragma unroll
    for (int r = 0; r < 16; ++r) {
        float s  = rs[r][0]  + rs[r][1]  + rs[r][2]  + rs[r][3];
        float s2 = rs2[r][0] + rs2[r][1] + rs2[r][2] + rs2[r][3];
        float mu  = s  * (1.f / MW);
        float var = s2 * (1.f / MW) - mu * mu;
        float o = (y[r] - mu) * rsqrtf(var + EPSV);
        out[((size_t)n * MW + c) * L_TOT + l0 + r] = g * o + be;
    }
}

// ---------------------------------------------------------------------------
extern "C" void kernel_launch(void* const* d_in, const int* in_sizes, int n_in,
                              void* d_out, int out_size, void* d_ws, size_t ws_size,
                              hipStream_t stream) {
    const float* x  = (const float*)d_in[0];
    const float* Wq = (const float*)d_in[1];
    const float* bq = (const float*)d_in[2];
    const float* Wk = (const float*)d_in[3];
    const float* bk = (const float*)d_in[4];
    const float* Wv = (const float*)d_in[5];
    const float* bv = (const float*)d_in[6];
    const float* W1 = (const float*)d_in[7];
    const float* b1 = (const float*)d_in[8];
    const float* W2 = (const float*)d_in[9];
    const float* b2 = (const float*)d_in[10];
    const float* gm = (const float*)d_in[11];
    const float* bt = (const float*)d_in[12];
    float* out = (float*)d_out;

    // choose chunk count from ws_size (deterministic)
    const size_t QKV  = (size_t)NH * NB * L_TOT * NF;   // 1,179,648 floats each
    const size_t STAT = (size_t)16 * L_TOT;             // 36,864 floats
    const size_t HEADS = (size_t)NB * L_TOT * MW;       // 1,179,648 floats
    int CH = 1;
    for (int cc = 8; cc >= 2; cc >>= 1) {
        size_t need = (3 * QKV + 2 * STAT + (size_t)cc * (2 * STAT + HEADS)) * sizeof(float);
        if (need <= ws_size) { CH = cc; break; }
    }

    float* ws = (float*)d_ws;
    float* Qw = ws;
    float* Kw = Qw + QKV;
    float* Vw = Kw + QKV;
    float* cpart = Vw + QKV;             // CH*STAT
    float* zpart = cpart + (size_t)CH * STAT;
    float* cmaxw = zpart + (size_t)CH * STAT;
    float* zinvw = cmaxw + STAT;
    float* partA = zinvw + STAT;         // CH*HEADS

    k_proj<<<dim3(NB * (L_TOT / 16)), dim3(256), 0, stream>>>(
        x, Wq, bq, Wk, bk, Wv, bv, Qw, Kw, Vw);
    k_colstats<<<dim3(16, L_TOT / 256, CH), dim3(256), 0, stream>>>(
        Qw, Kw, cpart, zpart, CH);
    k_colfinish<<<dim3(16 * L_TOT / 256), dim3(256), 0, stream>>>(
        cpart, zpart, cmaxw, zinvw, CH);
    k_attn<<<dim3(16, L_TOT / 256, CH), dim3(256), 0, stream>>>(
        Qw, Kw, Vw, cmaxw, zinvw, partA, CH);
    k_mlp<<<dim3(NB * (L_TOT / 16)), dim3(256), 0, stream>>>(
        partA, W1, b1, W2, b2, gm, bt, out, CH);
}

// Round 3
// 201.176 us; speedup vs baseline: 3.3046x; 3.3046x over previous
//
#include <hip/hip_runtime.h>
#include <hip/hip_bf16.h>
#include <stdint.h>

// Problem constants
#define L_TOT 2304   // 48*48
#define D_IN  64
#define NF    32     // features per head
#define NH    8      // heads
#define NB    2      // batch
#define MW    256    // MLP width = NH*NF
#define CHS   4      // l-chunks for stats pass
#define NSTRIP (L_TOT/32)   // 72 m-strips

constexpr float EPSV  = 1e-5f;
constexpr float SCALE = 0.17677669529663687f;  // 1/sqrt(32)
constexpr float SHIFT = 20.0f;                 // softmax exp shift (s >= 0 always)

typedef __bf16  bf16x8  __attribute__((ext_vector_type(8)));
typedef float   f32x16  __attribute__((ext_vector_type(16)));

union U32x4BF { uint32_t u[4]; bf16x8 v; };

// Pack two f32 -> one u32 of two bf16 (element 0 = low halfword = a).
// Definitionally order-correct (replaces v_cvt_pk_bf16_f32 asm whose
// operand->lo/hi order was the one unverified atom in R2).
static __device__ __forceinline__ uint32_t pack_bf16(float a, float b) {
    union { __bf16 h[2]; uint32_t u; } r;
    r.h[0] = (__bf16)a;
    r.h[1] = (__bf16)b;
    return r.u;
}

// ---------------------------------------------------------------------------
// Kernel 1: fused projection (Q,K,V) + bias + InstanceNorm(32) + ReLU -> bf16
//   Qb [hn][l][32] (pre-scaled by 1/sqrt(32)), Kb [hn][l][32],
//   Vt [hn][strip][f][32m]  (transposed via LDS for >=16B stores)
// block = 256 (8h x 32f), 16 l-rows per block, grid = NB*144 = 288
// ---------------------------------------------------------------------------
__global__ __launch_bounds__(256) void k_proj(
    const float* __restrict__ x,
    const float* __restrict__ Wq, const float* __restrict__ bq,
    const float* __restrict__ Wk, const float* __restrict__ bk,
    const float* __restrict__ Wv, const float* __restrict__ bv,
    __hip_bfloat16* __restrict__ Qo, __hip_bfloat16* __restrict__ Ko,
    __hip_bfloat16* __restrict__ Vt)
{
    const int tile = blockIdx.x;
    const int n  = tile / (L_TOT / 16);
    const int l0 = (tile % (L_TOT / 16)) * 16;
    const int tid = threadIdx.x;
    const int h = tid >> 5, f = tid & 31;

    __shared__ float xs[16][D_IN];
    __shared__ __align__(16) __hip_bfloat16 vs_t[8][32][16];

    for (int i = tid; i < 16 * D_IN; i += 256) {
        int d = i >> 4, r = i & 15;
        xs[r][d] = x[n * D_IN * L_TOT + d * L_TOT + l0 + r];
    }
    __syncthreads();

    const float* Ws[3] = {Wq, Wk, Wv};
    const float* bs[3] = {bq, bk, bv};

    #pragma unroll
    for (int mtx = 0; mtx < 3; ++mtx) {
        float acc[16];
        #pragma unroll
        for (int r = 0; r < 16; ++r) acc[r] = 0.f;
        const float* W = Ws[mtx] + h * D_IN * NF + f;
        for (int d = 0; d < D_IN; ++d) {
            float w = W[d * NF];
            #pragma unroll
            for (int r = 0; r < 16; ++r) acc[r] += xs[r][d] * w;
        }
        const float bias = bs[mtx][h * NF + f];
        const int hn = h * NB + n;
        #pragma unroll
        for (int r = 0; r < 16; ++r) {
            float v = acc[r] + bias;
            float s = v, s2 = v * v;
            #pragma unroll
            for (int o = 16; o >= 1; o >>= 1) {
                s  += __shfl_xor(s,  o, 32);
                s2 += __shfl_xor(s2, o, 32);
            }
            float mu  = s  * (1.f / 32);
            float var = s2 * (1.f / 32) - mu * mu;
            float y = fmaxf((v - mu) * rsqrtf(var + EPSV), 0.f);
            if (mtx == 0) {
                Qo[((size_t)hn * L_TOT + l0 + r) * NF + f] = __float2bfloat16(y * SCALE);
            } else if (mtx == 1) {
                Ko[((size_t)hn * L_TOT + l0 + r) * NF + f] = __float2bfloat16(y);
            } else {
                vs_t[h][f][r] = __float2bfloat16(y);
            }
        }
    }
    __syncthreads();
    // coalesced-ish 16B writes of V^T: 512 chunks of 8 m-elements
    const int strip = l0 >> 5;
    const int mbase = l0 & 31;
    for (int cgrp = tid; cgrp < 512; cgrp += 256) {
        int h2 = cgrp >> 6, f2 = (cgrp >> 1) & 31, half = cgrp & 1;
        int hn2 = h2 * NB + n;
        bf16x8* dst = reinterpret_cast<bf16x8*>(
            Vt + ((size_t)(hn2 * NSTRIP + strip) * 32 + f2) * 32 + mbase + half * 8);
        *dst = *reinterpret_cast<const bf16x8*>(&vs_t[h2][f2][half * 8]);
    }
}

// ---------------------------------------------------------------------------
// Kernel 2: column softmax stats. S^T = K @ Q^T per 32-m strip via MFMA.
// Z[m] = sum_l exp(s - 20). Stored permuted: zpart[chunk][hn][strip*32 + hi*16 + r]
// block = 256 (4 indep waves), grid = (18, 16 hn, CHS)
// ---------------------------------------------------------------------------
__global__ __launch_bounds__(256) void k_stats(
    const __hip_bfloat16* __restrict__ Qb, const __hip_bfloat16* __restrict__ Kb,
    float* __restrict__ zpart)
{
    const int w = threadIdx.x >> 6;
    const int strip = blockIdx.x * 4 + w;
    const int hn = blockIdx.y;
    const int chunk = blockIdx.z;
    const int lane = threadIdx.x & 63;
    const int c = lane & 31, hi = lane >> 5;

    const bf16x8* kp = reinterpret_cast<const bf16x8*>(
        Kb + ((size_t)hn * L_TOT + strip * 32 + c) * NF);
    const bf16x8 ka0 = kp[hi];      // f 0..15 across the two half-waves
    const bf16x8 ka1 = kp[2 + hi];  // f 16..31

    float Zr[16];
    #pragma unroll
    for (int r = 0; r < 16; ++r) Zr[r] = 0.f;

    for (int it = 0; it < (L_TOT / 32) / CHS; ++it) {
        const int l0 = (chunk * ((L_TOT / 32) / CHS) + it) * 32;
        const bf16x8* qp = reinterpret_cast<const bf16x8*>(
            Qb + ((size_t)hn * L_TOT + l0 + c) * NF);
        bf16x8 qb0 = qp[hi];
        bf16x8 qb1 = qp[2 + hi];
        f32x16 s16 = {};
        s16 = __builtin_amdgcn_mfma_f32_32x32x16_bf16(ka0, qb0, s16, 0, 0, 0);
        s16 = __builtin_amdgcn_mfma_f32_32x32x16_bf16(ka1, qb1, s16, 0, 0, 0);
        #pragma unroll
        for (int r = 0; r < 16; ++r) Zr[r] += __expf(s16[r] - SHIFT);
    }
    // reduce across the 32 col-lanes of each half
    #pragma unroll
    for (int r = 0; r < 16; ++r) {
        #pragma unroll
        for (int o = 16; o >= 1; o >>= 1) Zr[r] += __shfl_xor(Zr[r], o, 64);
    }
    if (c == 0) {
        float4* zp = reinterpret_cast<float4*>(
            zpart + ((size_t)chunk * 16 + hn) * L_TOT + strip * 32 + hi * 16);
        zp[0] = make_float4(Zr[0], Zr[1], Zr[2], Zr[3]);
        zp[1] = make_float4(Zr[4], Zr[5], Zr[6], Zr[7]);
        zp[2] = make_float4(Zr[8], Zr[9], Zr[10], Zr[11]);
        zp[3] = make_float4(Zr[12], Zr[13], Zr[14], Zr[15]);
    }
}

// Combine chunks -> lse (same permuted layout)
__global__ __launch_bounds__(256) void k_finish(
    const float* __restrict__ zpart, float* __restrict__ lse_p)
{
    const int idx = blockIdx.x * 256 + threadIdx.x;  // hn*L + perm(m)
    float Z = 0.f;
    #pragma unroll
    for (int cc = 0; cc < CHS; ++cc) Z += zpart[(size_t)cc * 16 * L_TOT + idx];
    lse_p[idx] = SHIFT + logf(Z);
}

// ---------------------------------------------------------------------------
// Kernel 3: apply. Per 32-l tile: S^T tile via MFMA, p = exp(s - lse[m]),
// bit-pack + shfl_xor(32) relayout into A-fragments, PV via MFMA.
// Partial over m-chunks -> partA[chunk][n][l][h*32+f]
// block = 256 (4 indep waves), grid = (18, 16 hn, CH)
// ---------------------------------------------------------------------------
__global__ __launch_bounds__(256) void k_apply(
    const __hip_bfloat16* __restrict__ Qb, const __hip_bfloat16* __restrict__ Kb,
    const __hip_bfloat16* __restrict__ Vt, const float* __restrict__ lse_p,
    float* __restrict__ partA, int CH)
{
    const int w = threadIdx.x >> 6;
    const int ltile = blockIdx.x * 4 + w;
    const int l0 = ltile * 32;
    const int hn = blockIdx.y;
    const int chunk = blockIdx.z;
    const int lane = threadIdx.x & 63;
    const int c = lane & 31, hi = lane >> 5;

    const bf16x8* qp = reinterpret_cast<const bf16x8*>(
        Qb + ((size_t)hn * L_TOT + l0 + c) * NF);
    const bf16x8 qb0 = qp[hi];
    const bf16x8 qb1 = qp[2 + hi];

    f32x16 acc = {};
    const int nsteps = NSTRIP / CH;

    for (int it = 0; it < nsteps; ++it) {
        const int st = chunk * nsteps + it;
        // S^T tile
        const bf16x8* kp = reinterpret_cast<const bf16x8*>(
            Kb + ((size_t)hn * L_TOT + st * 32 + c) * NF);
        f32x16 s16 = {};
        s16 = __builtin_amdgcn_mfma_f32_32x32x16_bf16(kp[hi], qb0, s16, 0, 0, 0);
        s16 = __builtin_amdgcn_mfma_f32_32x32x16_bf16(kp[2 + hi], qb1, s16, 0, 0, 0);

        // lse for this lane's 16 rows (permuted layout, broadcast within half)
        const float4* lp = reinterpret_cast<const float4*>(
            lse_p + (size_t)hn * L_TOT + st * 32 + hi * 16);
        float lv[16];
        #pragma unroll
        for (int q = 0; q < 4; ++q) {
            float4 t = lp[q];
            lv[4 * q + 0] = t.x; lv[4 * q + 1] = t.y;
            lv[4 * q + 2] = t.z; lv[4 * q + 3] = t.w;
        }
        float p[16];
        #pragma unroll
        for (int r = 0; r < 16; ++r) p[r] = __expf(s16[r] - lv[r]);

        // pack to bf16 pairs: wp[q] = (row 2q, row 2q+1) of this half
        uint32_t wp[8];
        #pragma unroll
        for (int q = 0; q < 8; ++q) wp[q] = pack_bf16(p[2 * q], p[2 * q + 1]);

        // cross-half exchange: build A-fragments for PV
        // t0 (m_local 0..15): half0 needs half1's w0,w1 ; half1 needs half0's w2,w3
        uint32_t sendA = hi ? wp[0] : wp[2];
        uint32_t sendB = hi ? wp[1] : wp[3];
        uint32_t rA = (uint32_t)__shfl_xor((int)sendA, 32, 64);
        uint32_t rB = (uint32_t)__shfl_xor((int)sendB, 32, 64);
        U32x4BF fragP0;
        fragP0.u[0] = hi ? rA    : wp[0];
        fragP0.u[1] = hi ? rB    : wp[1];
        fragP0.u[2] = hi ? wp[2] : rA;
        fragP0.u[3] = hi ? wp[3] : rB;
        // t1 (m_local 16..31): half0 needs half1's w4,w5 ; half1 needs half0's w6,w7
        uint32_t sendC = hi ? wp[4] : wp[6];
        uint32_t sendD = hi ? wp[5] : wp[7];
        uint32_t rC = (uint32_t)__shfl_xor((int)sendC, 32, 64);
        uint32_t rD = (uint32_t)__shfl_xor((int)sendD, 32, 64);
        U32x4BF fragP1;
        fragP1.u[0] = hi ? rC    : wp[4];
        fragP1.u[1] = hi ? rD    : wp[5];
        fragP1.u[2] = hi ? wp[6] : rC;
        fragP1.u[3] = hi ? wp[7] : rD;

        // V B-fragments: Vt[hn][st][f=c][m]
        const bf16x8* vp = reinterpret_cast<const bf16x8*>(
            Vt + ((size_t)(hn * NSTRIP + st) * 32 + c) * 32);
        acc = __builtin_amdgcn_mfma_f32_32x32x16_bf16(fragP0.v, vp[hi], acc, 0, 0, 0);
        acc = __builtin_amdgcn_mfma_f32_32x32x16_bf16(fragP1.v, vp[2 + hi], acc, 0, 0, 0);
    }

    const int n = hn & 1, h = hn >> 1;
    float* outp = partA + (size_t)chunk * (NB * L_TOT * MW)
                + ((size_t)(n * L_TOT + l0)) * MW + h * NF + c;
    #pragma unroll
    for (int r = 0; r < 16; ++r) {
        int row = (r & 3) + 8 * (r >> 2) + 4 * hi;
        outp[(size_t)row * MW] = acc[r];
    }
}

// ---------------------------------------------------------------------------
// Kernel 4: heads = sum(partA) ; m=relu(relu(h@W1+b1)@W2+b2) ;
//           o = gamma*inorm(m+h)+beta ; out[n,c,l] (transposed store)
// ---------------------------------------------------------------------------
__global__ __launch_bounds__(256) void k_mlp(
    const float* __restrict__ partA,
    const float* __restrict__ W1, const float* __restrict__ b1,
    const float* __restrict__ W2, const float* __restrict__ b2,
    const float* __restrict__ gamma, const float* __restrict__ beta,
    float* __restrict__ out, int CH)
{
    const int tile = blockIdx.x;
    const int n  = tile / (L_TOT / 16);
    const int l0 = (tile % (L_TOT / 16)) * 16;
    const int c = threadIdx.x;
    const int wid = c >> 6, lane = c & 63;

    __shared__ float hs[16][MW];
    __shared__ float ms[16][MW];

    for (int idx = threadIdx.x; idx < 16 * MW; idx += 256) {
        int r = idx >> 8, i = idx & 255;
        float v = 0.f;
        for (int k = 0; k < CH; ++k)
            v += partA[(size_t)k * (NB * L_TOT * MW) + ((size_t)n * L_TOT + l0 + r) * MW + i];
        hs[r][i] = v;
    }
    __syncthreads();

    float acc[16];
    #pragma unroll
    for (int r = 0; r < 16; ++r) acc[r] = 0.f;
    for (int i = 0; i < MW; i += 4) {
        float w0 = W1[(i + 0) * MW + c];
        float w1 = W1[(i + 1) * MW + c];
        float w2 = W1[(i + 2) * MW + c];
        float w3 = W1[(i + 3) * MW + c];
        #pragma unroll
        for (int r = 0; r < 16; ++r) {
            const float4 h4 = *(const float4*)&hs[r][i];
            acc[r] += h4.x * w0 + h4.y * w1 + h4.z * w2 + h4.w * w3;
        }
    }
    {
        const float bb = b1[c];
        #pragma unroll
        for (int r = 0; r < 16; ++r) ms[r][c] = fmaxf(acc[r] + bb, 0.f);
    }
    __syncthreads();

    #pragma unroll
    for (int r = 0; r < 16; ++r) acc[r] = 0.f;
    for (int i = 0; i < MW; i += 4) {
        float w0 = W2[(i + 0) * MW + c];
        float w1 = W2[(i + 1) * MW + c];
        float w2 = W2[(i + 2) * MW + c];
        float w3 = W2[(i + 3) * MW + c];
        #pragma unroll
        for (int r = 0; r < 16; ++r) {
            const float4 h4 = *(const float4*)&ms[r][i];
            acc[r] += h4.x * w0 + h4.y * w1 + h4.z * w2 + h4.w * w3;
        }
    }

    float y[16];
    {
        const float bb = b2[c];
        #pragma unroll
        for (int r = 0; r < 16; ++r) y[r] = fmaxf(acc[r] + bb, 0.f) + hs[r][c];
    }

    __shared__ float rs[16][4], rs2[16][4];
    #pragma unroll
    for (int r = 0; r < 16; ++r) {
        float s = y[r], s2 = y[r] * y[r];
        #pragma unroll
        for (int o = 32; o >= 1; o >>= 1) { s += __shfl_xor(s, o, 64); s2 += __shfl_xor(s2, o, 64); }
        if (lane == 0) { rs[r][wid] = s; rs2[r][wid] = s2; }
    }
    __syncthreads();

    const float g = gamma[c], be = beta[c];
    #pragma unroll
    for (int r = 0; r < 16; ++r) {
        float s  = rs[r][0]  + rs[r][1]  + rs[r][2]  + rs[r][3];
        float s2 = rs2[r][0] + rs2[r][1] + rs2[r][2] + rs2[r][3];
        float mu  = s  * (1.f / MW);
        float var = s2 * (1.f / MW) - mu * mu;
        float o = (y[r] - mu) * rsqrtf(var + EPSV);
        out[((size_t)n * MW + c) * L_TOT + l0 + r] = g * o + be;
    }
}

// ---------------------------------------------------------------------------
extern "C" void kernel_launch(void* const* d_in, const int* in_sizes, int n_in,
                              void* d_out, int out_size, void* d_ws, size_t ws_size,
                              hipStream_t stream) {
    const float* x  = (const float*)d_in[0];
    const float* Wq = (const float*)d_in[1];
    const float* bq = (const float*)d_in[2];
    const float* Wk = (const float*)d_in[3];
    const float* bk = (const float*)d_in[4];
    const float* Wv = (const float*)d_in[5];
    const float* bv = (const float*)d_in[6];
    const float* W1 = (const float*)d_in[7];
    const float* b1 = (const float*)d_in[8];
    const float* W2 = (const float*)d_in[9];
    const float* b2 = (const float*)d_in[10];
    const float* gm = (const float*)d_in[11];
    const float* bt = (const float*)d_in[12];
    float* out = (float*)d_out;

    const size_t QKVE = (size_t)16 * L_TOT * NF;         // 1,179,648 bf16 elems
    const size_t BF_BYTES = 3 * QKVE * sizeof(__hip_bfloat16);  // 7,077,888
    const size_t ZN = (size_t)CHS * 16 * L_TOT;          // zpart floats
    const size_t LN = (size_t)16 * L_TOT;                // lse floats
    const size_t HEADS = (size_t)NB * L_TOT * MW;        // partA floats per chunk

    __hip_bfloat16* Qb = (__hip_bfloat16*)d_ws;
    __hip_bfloat16* Kb = Qb + QKVE;
    __hip_bfloat16* Vt = Kb + QKVE;
    float* zpart = (float*)((char*)d_ws + BF_BYTES);
    float* lse_p = zpart + ZN;
    float* partA = lse_p + LN;

    const size_t fixed = BF_BYTES + (ZN + LN) * sizeof(float);
    int CH = 1;
    for (int cc = 4; cc >= 2; cc >>= 1) {
        if (fixed + (size_t)cc * HEADS * sizeof(float) <= ws_size) { CH = cc; break; }
    }

    k_proj<<<dim3(NB * (L_TOT / 16)), dim3(256), 0, stream>>>(
        x, Wq, bq, Wk, bk, Wv, bv, Qb, Kb, Vt);
    k_stats<<<dim3(NSTRIP / 4, 16, CHS), dim3(256), 0, stream>>>(Qb, Kb, zpart);
    k_finish<<<dim3(16 * L_TOT / 256), dim3(256), 0, stream>>>(zpart, lse_p);
    k_apply<<<dim3(NSTRIP / 4, 16, CH), dim3(256), 0, stream>>>(
        Qb, Kb, Vt, lse_p, partA, CH);
    k_mlp<<<dim3(NB * (L_TOT / 16)), dim3(256), 0, stream>>>(
        partA, W1, b1, W2, b2, gm, bt, out, CH);
}